// Round 9
// baseline (163.109 us; speedup 1.0000x reference)
//
#include <hip/hip_runtime.h>

#define BATCH 16
#define NX 1024
#define NY 1024
#define CHUNK 8           // traffic-minimal (R0/R7: FETCH ~73 MB)
#define PLANE (NX * NY)

typedef float v4f __attribute__((ext_vector_type(4)));

// Shared per-row raw data; halo scalars only for cross-wave lanes
struct RawS { v4f a0, a1, b0, b1, b2; float a1l, b1l, b2l, a1r, b1r, b2r; };
// Per-row f data
struct RawF { v4f f; float fl, fr; };
// Shuffled y-halo grid values
struct Halo { float a1m, b1m, b2m, a1p, b1p, b2p; };
// Per-row linear coefficients.
// out[x] = f + dt*( ep(x+1) + es(x) + en(x-1) ), per element:
//   ep = f*xp + 0.25*(te[e+2]-te[e])   (xp = 0.5*(b0-a0), te = b2*f)
//   en = f*xm - 0.25*(te[e+2]-te[e])   (xm = 0.5*(a0+b0))
//   es = f*c0x + cp*f_y+1 + cm*f_y-1
// K[4]/T[3]: one-sided y-boundary sets, valid only in lanes 0 / 255.
struct Coef { float cp[4], cm[4], c0x[4], xp[4], xm[4], b2w[6], K[4], T[3]; };
struct RowI { float ep[4], es[4], en[4], fc[4]; };
// Full-form row (original math) for the x-boundary one-sided stencils
struct RowB { float pa[4], rr[4], tt[4], yc[4], fc[4]; };

__device__ __forceinline__ RawS load_rawS(int xx, int y0, int tid,
    const float* __restrict__ A0, const float* __restrict__ A1,
    const float* __restrict__ B0, const float* __restrict__ B1,
    const float* __restrict__ B2)
{
    const int base = xx * NY + y0;
    RawS r;
    r.a0 = *(const v4f*)(A0 + base);
    r.a1 = *(const v4f*)(A1 + base);
    r.b0 = *(const v4f*)(B0 + base);
    r.b1 = *(const v4f*)(B1 + base);
    r.b2 = *(const v4f*)(B2 + base);
    const int lane = tid & 63;
    const bool nl = (lane == 0)  && (tid > 0);    // cross-wave left halo
    const bool nr = (lane == 63) && (tid < 255);  // cross-wave right halo
    r.a1l = nl ? A1[base - 1] : 0.0f;
    r.b1l = nl ? B1[base - 1] : 0.0f;
    r.b2l = nl ? B2[base - 1] : 0.0f;
    r.a1r = nr ? A1[base + 4] : 0.0f;
    r.b1r = nr ? B1[base + 4] : 0.0f;
    r.b2r = nr ? B2[base + 4] : 0.0f;
    return r;
}

__device__ __forceinline__ RawF load_rawF(int xx, int y0, int tid,
    const float* __restrict__ fb)
{
    const int base = xx * NY + y0;
    RawF r;
    r.f = *(const v4f*)(fb + base);
    const int lane = tid & 63;
    const bool nl = (lane == 0)  && (tid > 0);
    const bool nr = (lane == 63) && (tid < 255);
    r.fl = nl ? fb[base - 1] : 0.0f;
    r.fr = nr ? fb[base + 4] : 0.0f;
    return r;
}

__device__ __forceinline__ Halo make_halo(const RawS& rs, int tid)
{
    const int lane = tid & 63;
    Halo h;
    h.a1m = __shfl_up(rs.a1.w, 1);   h.b1m = __shfl_up(rs.b1.w, 1);
    h.b2m = __shfl_up(rs.b2.w, 1);
    h.a1p = __shfl_down(rs.a1.x, 1); h.b1p = __shfl_down(rs.b1.x, 1);
    h.b2p = __shfl_down(rs.b2.x, 1);
    if (lane == 0)  { h.a1m = rs.a1l; h.b1m = rs.b1l; h.b2m = rs.b2l; }
    if (lane == 63) { h.a1p = rs.a1r; h.b1p = rs.b1r; h.b2p = rs.b2r; }
    return h;
}

__device__ __forceinline__ Coef make_coef(const RawS& g, const Halo& h, int tid)
{
    Coef c;
    const float a1w[6] = { h.a1m, g.a1.x, g.a1.y, g.a1.z, g.a1.w, h.a1p };
    const float b1w[6] = { h.b1m, g.b1.x, g.b1.y, g.b1.z, g.b1.w, h.b1p };
    c.b2w[0] = h.b2m; c.b2w[1] = g.b2.x; c.b2w[2] = g.b2.y;
    c.b2w[3] = g.b2.z; c.b2w[4] = g.b2.w; c.b2w[5] = h.b2p;
    #pragma unroll
    for (int e = 0; e < 4; ++e) {
        c.xp[e]  = 0.5f * (g.b0[e] - g.a0[e]);
        c.xm[e]  = 0.5f * (g.b0[e] + g.a0[e]);
        c.c0x[e] = -(g.b0[e] + b1w[e + 1]);
        c.cp[e]  = 0.5f * (b1w[e + 2] - a1w[e + 2]);
        c.cm[e]  = 0.5f * (a1w[e]     + b1w[e]);
    }
    if (tid == 0) {        // y=0 one-sided
        c.K[0] = -g.b0.x + 1.5f * g.a1.x + g.b1.x;
        c.K[1] = -2.0f * g.a1.y - 2.5f * g.b1.y;
        c.K[2] =  0.5f * g.a1.z + 2.0f * g.b1.z;
        c.K[3] = -0.5f * g.b1.w;
        c.T[0] = -0.75f * g.b2.x; c.T[1] = g.b2.y; c.T[2] = -0.25f * g.b2.z;
    }
    if (tid == 255) {      // y=NY-1 one-sided
        c.K[0] = -g.b0.w - 1.5f * g.a1.w + g.b1.w;
        c.K[1] =  2.0f * g.a1.z - 2.5f * g.b1.z;
        c.K[2] = -0.5f * g.a1.y + 2.0f * g.b1.y;
        c.K[3] = -0.5f * g.b1.x;
        c.T[0] = 0.75f * g.b2.w; c.T[1] = -g.b2.z; c.T[2] = 0.25f * g.b2.y;
    }
    return c;
}

__device__ __forceinline__ RowI convertI(const Coef& cf, const RawF& rf, int tid)
{
    const int lane = tid & 63;
    float fm = __shfl_up(rf.f.w, 1);
    float fp = __shfl_down(rf.f.x, 1);
    if (lane == 0)  fm = rf.fl;
    if (lane == 63) fp = rf.fr;
    const float fw[6] = { fm, rf.f.x, rf.f.y, rf.f.z, rf.f.w, fp };
    float te[6];
    #pragma unroll
    for (int w = 0; w < 6; ++w) te[w] = cf.b2w[w] * fw[w];
    RowI o;
    #pragma unroll
    for (int e = 0; e < 4; ++e) {
        const float d = 0.25f * (te[e + 2] - te[e]);
        o.fc[e] = fw[e + 1];
        o.ep[e] = fw[e + 1] * cf.xp[e]  + d;
        o.en[e] = fw[e + 1] * cf.xm[e]  - d;
        o.es[e] = fw[e + 1] * cf.c0x[e] + cf.cp[e] * fw[e + 2] + cf.cm[e] * fw[e];
    }
    if (tid == 0) {        // garbage fw[0] fully overridden here
        o.es[0] = cf.K[0] * fw[1] + cf.K[1] * fw[2] + cf.K[2] * fw[3] + cf.K[3] * fw[4];
        const float h = cf.T[0] * fw[1] + cf.T[1] * fw[2] + cf.T[2] * fw[3];
        o.ep[0] = fw[1] * cf.xp[0] + h;
        o.en[0] = fw[1] * cf.xm[0] - h;
    }
    if (tid == 255) {      // garbage fw[5] fully overridden here
        o.es[3] = cf.K[0] * fw[4] + cf.K[1] * fw[3] + cf.K[2] * fw[2] + cf.K[3] * fw[1];
        const float h = cf.T[0] * fw[4] + cf.T[1] * fw[3] + cf.T[2] * fw[2];
        o.ep[3] = fw[4] * cf.xp[3] + h;
        o.en[3] = fw[4] * cf.xm[3] - h;
    }
    return o;
}

__device__ __forceinline__ RowB convertB(const RawS& g, const Halo& h,
                                         const RawF& rf, int tid)
{
    const int lane = tid & 63;
    float fm = __shfl_up(rf.f.w, 1);
    float fp = __shfl_down(rf.f.x, 1);
    if (lane == 0)  fm = rf.fl;
    if (lane == 63) fp = rf.fr;
    const float fw[6] = { fm, rf.f.x, rf.f.y, rf.f.z, rf.f.w, fp };
    const float qe[6] = { h.a1m * fw[0], g.a1.x * fw[1], g.a1.y * fw[2],
                          g.a1.z * fw[3], g.a1.w * fw[4], h.a1p * fw[5] };
    const float se[6] = { h.b1m * fw[0], g.b1.x * fw[1], g.b1.y * fw[2],
                          g.b1.z * fw[3], g.b1.w * fw[4], h.b1p * fw[5] };
    const float te[6] = { h.b2m * fw[0], g.b2.x * fw[1], g.b2.y * fw[2],
                          g.b2.z * fw[3], g.b2.w * fw[4], h.b2p * fw[5] };
    RowB o;
    o.fc[0] = fw[1]; o.fc[1] = fw[2]; o.fc[2] = fw[3]; o.fc[3] = fw[4];
    o.pa[0] = g.a0.x * fw[1]; o.pa[1] = g.a0.y * fw[2];
    o.pa[2] = g.a0.z * fw[3]; o.pa[3] = g.a0.w * fw[4];
    o.rr[0] = g.b0.x * fw[1]; o.rr[1] = g.b0.y * fw[2];
    o.rr[2] = g.b0.z * fw[3]; o.rr[3] = g.b0.w * fw[4];
    #pragma unroll
    for (int i = 0; i < 4; ++i) {
        const float dq  = 0.5f * (qe[i + 2] - qe[i]);
        const float d2s = se[i + 2] - 2.0f * se[i + 1] + se[i];
        o.tt[i] = 0.5f * (te[i + 2] - te[i]);
        o.yc[i] = -dq + 0.5f * d2s;
    }
    if (tid == 0) {
        const float dq  = 0.5f * (-3.0f * qe[1] + 4.0f * qe[2] - qe[3]);
        const float d2s = 2.0f * se[1] - 5.0f * se[2] + 4.0f * se[3] - se[4];
        o.tt[0] = 0.5f * (-3.0f * te[1] + 4.0f * te[2] - te[3]);
        o.yc[0] = -dq + 0.5f * d2s;
    }
    if (tid == 255) {
        const float dq  = 0.5f * (3.0f * qe[4] - 4.0f * qe[3] + qe[2]);
        const float d2s = 2.0f * se[4] - 5.0f * se[3] + 4.0f * se[2] - se[1];
        o.tt[3] = 0.5f * (3.0f * te[4] - 4.0f * te[3] + te[2]);
        o.yc[3] = -dq + 0.5f * d2s;
    }
    return o;
}

__global__ __launch_bounds__(256) void fp2d_kernel(
    const float* __restrict__ f,
    const float* __restrict__ Ag,
    const float* __restrict__ Bg,
    const float* __restrict__ dt,
    float* __restrict__ out)
{
    const int tid = threadIdx.x;
    const int y0  = tid * 4;
    const int x0  = blockIdx.x * CHUNK;   // xc fastest; same-x blocks across batches
    const int b   = blockIdx.y;           //   share an XCD -> grid rows stay L2-local

    const float* __restrict__ A0 = Ag;
    const float* __restrict__ A1 = Ag + PLANE;
    const float* __restrict__ B0 = Bg;
    const float* __restrict__ B1 = Bg + PLANE;
    const float* __restrict__ B2 = Bg + 2 * PLANE;

    const float* __restrict__ fb = f   + (size_t)b * PLANE;
    float* __restrict__ ob       = out + (size_t)b * PLANE;
    const float dtv = dt[b];

    const int cs = (x0 == 0) ? 1 : x0;
    const int ce = (x0 + CHUNK == NX) ? NX - 2 : x0 + CHUNK - 1;

    // Persistent state: m-row needs only en; c-row needs es/en/fc.
    float mEn[4], cEs[4], cEn[4], cFc[4];

    // Prologue: rows cs-1, cs converted; row cs+1 raw (depth-1 prefetch)
    RawS sP;
    RawF fP;
    {
        RawS sM = load_rawS(cs - 1, y0, tid, A0, A1, B0, B1, B2);
        RawS sC = load_rawS(cs,     y0, tid, A0, A1, B0, B1, B2);
        sP      = load_rawS(cs + 1, y0, tid, A0, A1, B0, B1, B2);
        RawF fM = load_rawF(cs - 1, y0, tid, fb);
        RawF fC = load_rawF(cs,     y0, tid, fb);
        fP      = load_rawF(cs + 1, y0, tid, fb);
        const Coef cfM = make_coef(sM, make_halo(sM, tid), tid);
        const Coef cfC = make_coef(sC, make_halo(sC, tid), tid);
        RowI rm = convertI(cfM, fM, tid);
        RowI rc = convertI(cfC, fC, tid);
        #pragma unroll
        for (int i = 0; i < 4; ++i) {
            mEn[i] = rm.en[i];
            cEs[i] = rc.es[i]; cEn[i] = rc.en[i]; cFc[i] = rc.fc[i];
        }
    }

    for (int x = cs; x <= ce; ++x) {
        const int xn = (x + 2 < NX) ? x + 2 : NX - 1;
        RawS sN = load_rawS(xn, y0, tid, A0, A1, B0, B1, B2);   // prefetch
        RawF fN = load_rawF(xn, y0, tid, fb);

        const Halo hP = make_halo(sP, tid);
        const Coef cf = make_coef(sP, hP, tid);
        RowI rp = convertI(cf, fP, tid);
        v4f o;
        #pragma unroll
        for (int i = 0; i < 4; ++i) {
            const float t = rp.ep[i] + cEs[i] + mEn[i];
            o[i] = fmaxf(fmaf(t, dtv, cFc[i]), 0.0f);
        }
        __builtin_nontemporal_store(o, (v4f*)(ob + x * NY + y0));
        #pragma unroll
        for (int i = 0; i < 4; ++i) {
            mEn[i] = cEn[i];
            cEs[i] = rp.es[i]; cEn[i] = rp.en[i]; cFc[i] = rp.fc[i];
        }
        sP = sN;
        fP = fN;
    }

    // x = 0 one-sided (first chunk only): row-by-row accumulation.
    // df = yc(r0) + sum_r wP[r]*pa_r + wR[r]*rr_r + wT[r]*tt_r
    if (x0 == 0) {
        const float wPx[4] = {  1.5f, -2.0f,  0.5f,  0.0f };
        const float wRx[4] = {  1.0f, -2.5f,  2.0f, -0.5f };
        const float wTx[4] = { -1.5f,  2.0f, -0.5f,  0.0f };
        float acc[4], fc0[4];
        #pragma unroll
        for (int r = 0; r < 4; ++r) {
            RawS g = load_rawS(r, y0, tid, A0, A1, B0, B1, B2);
            Halo h = make_halo(g, tid);
            RowB rb = convertB(g, h, load_rawF(r, y0, tid, fb), tid);
            #pragma unroll
            for (int i = 0; i < 4; ++i) {
                if (r == 0) { acc[i] = rb.yc[i]; fc0[i] = rb.fc[i]; }
                acc[i] += wPx[r] * rb.pa[i] + wRx[r] * rb.rr[i] + wTx[r] * rb.tt[i];
            }
        }
        v4f o;
        #pragma unroll
        for (int i = 0; i < 4; ++i)
            o[i] = fmaxf(fmaf(acc[i], dtv, fc0[i]), 0.0f);
        __builtin_nontemporal_store(o, (v4f*)(ob + y0));
    }

    // x = NX-1 one-sided (last chunk only)
    if (x0 + CHUNK == NX) {
        const float wPx[4] = { -1.5f,  2.0f, -0.5f,  0.0f };
        const float wRx[4] = {  1.0f, -2.5f,  2.0f, -0.5f };
        const float wTx[4] = {  1.5f, -2.0f,  0.5f,  0.0f };
        float acc[4], fc0[4];
        #pragma unroll
        for (int r = 0; r < 4; ++r) {
            RawS g = load_rawS(NX - 1 - r, y0, tid, A0, A1, B0, B1, B2);
            Halo h = make_halo(g, tid);
            RowB rb = convertB(g, h, load_rawF(NX - 1 - r, y0, tid, fb), tid);
            #pragma unroll
            for (int i = 0; i < 4; ++i) {
                if (r == 0) { acc[i] = rb.yc[i]; fc0[i] = rb.fc[i]; }
                acc[i] += wPx[r] * rb.pa[i] + wRx[r] * rb.rr[i] + wTx[r] * rb.tt[i];
            }
        }
        v4f o;
        #pragma unroll
        for (int i = 0; i < 4; ++i)
            o[i] = fmaxf(fmaf(acc[i], dtv, fc0[i]), 0.0f);
        __builtin_nontemporal_store(o, (v4f*)(ob + (size_t)(NX - 1) * NY + y0));
    }
}

extern "C" void kernel_launch(void* const* d_in, const int* in_sizes, int n_in,
                              void* d_out, int out_size, void* d_ws, size_t ws_size,
                              hipStream_t stream) {
    const float* f  = (const float*)d_in[0];
    const float* Ag = (const float*)d_in[1];
    const float* Bg = (const float*)d_in[2];
    const float* dt = (const float*)d_in[3];
    float* out = (float*)d_out;

    dim3 block(256, 1, 1);
    dim3 grid(NX / CHUNK, BATCH, 1);
    fp2d_kernel<<<grid, block, 0, stream>>>(f, Ag, Bg, dt, out);
}

// Round 10
// 150.119 us; speedup vs baseline: 1.0865x; 1.0865x over previous
//
#include <hip/hip_runtime.h>

#define BATCH 16
#define NX 1024
#define NY 1024
#define CHUNK 8           // traffic-minimal (R0/R7: FETCH ~73 MB)
#define NB 2              // batches per block: coefficients computed once, reused NB times
#define PLANE (NX * NY)

typedef float v4f __attribute__((ext_vector_type(4)));

// Shared (batch-independent) per-row raw data; halo scalars only for cross-wave lanes
struct RawS { v4f a0, a1, b0, b1, b2; float a1l, b1l, b2l, a1r, b1r, b2r; };
// Per-batch per-row raw data
struct RawF { v4f f; float fl, fr; };
// Shared shuffled y-halo grid values
struct Halo { float a1m, b1m, b2m, a1p, b1p, b2p; };
// Per-row, batch-independent linear coefficients.
// out[x] = f + dt*( ep(x+1) + es(x) + en(x-1) ), per element:
//   ep = f*xp + 0.25*(te[e+2]-te[e])   (xp = 0.5*(b0-a0), te = b2*f)
//   en = f*xm - 0.25*(te[e+2]-te[e])   (xm = 0.5*(a0+b0))
//   es = f*c0x + cp*f_y+1 + cm*f_y-1   (c0x=-(b0+b1), cp=0.5*(b1-a1)@y+1, cm=0.5*(a1+b1)@y-1)
// K[4]/T[3]: one-sided y-boundary sets, valid only in lanes 0 / 255.
struct Coef { float cp[4], cm[4], c0x[4], xp[4], xm[4], b2w[6], K[4], T[3]; };
struct RowI { float ep[4], es[4], en[4], fc[4]; };
// Full-form row (original math) for the x-boundary one-sided stencils
struct RowB { float pa[4], rr[4], tt[4], yc[4], fc[4]; };

__device__ __forceinline__ RawS load_rawS(int xx, int y0, int tid,
    const float* __restrict__ A0, const float* __restrict__ A1,
    const float* __restrict__ B0, const float* __restrict__ B1,
    const float* __restrict__ B2)
{
    const int base = xx * NY + y0;
    RawS r;
    r.a0 = *(const v4f*)(A0 + base);
    r.a1 = *(const v4f*)(A1 + base);
    r.b0 = *(const v4f*)(B0 + base);
    r.b1 = *(const v4f*)(B1 + base);
    r.b2 = *(const v4f*)(B2 + base);
    const int lane = tid & 63;
    const bool nl = (lane == 0)  && (tid > 0);    // cross-wave left halo
    const bool nr = (lane == 63) && (tid < 255);  // cross-wave right halo
    r.a1l = nl ? A1[base - 1] : 0.0f;
    r.b1l = nl ? B1[base - 1] : 0.0f;
    r.b2l = nl ? B2[base - 1] : 0.0f;
    r.a1r = nr ? A1[base + 4] : 0.0f;
    r.b1r = nr ? B1[base + 4] : 0.0f;
    r.b2r = nr ? B2[base + 4] : 0.0f;
    return r;
}

__device__ __forceinline__ RawF load_rawF(int xx, int y0, int tid,
    const float* __restrict__ fb)
{
    const int base = xx * NY + y0;
    RawF r;
    r.f = *(const v4f*)(fb + base);
    const int lane = tid & 63;
    const bool nl = (lane == 0)  && (tid > 0);
    const bool nr = (lane == 63) && (tid < 255);
    r.fl = nl ? fb[base - 1] : 0.0f;
    r.fr = nr ? fb[base + 4] : 0.0f;
    return r;
}

__device__ __forceinline__ Halo make_halo(const RawS& rs, int tid)
{
    const int lane = tid & 63;
    Halo h;
    h.a1m = __shfl_up(rs.a1.w, 1);   h.b1m = __shfl_up(rs.b1.w, 1);
    h.b2m = __shfl_up(rs.b2.w, 1);
    h.a1p = __shfl_down(rs.a1.x, 1); h.b1p = __shfl_down(rs.b1.x, 1);
    h.b2p = __shfl_down(rs.b2.x, 1);
    if (lane == 0)  { h.a1m = rs.a1l; h.b1m = rs.b1l; h.b2m = rs.b2l; }
    if (lane == 63) { h.a1p = rs.a1r; h.b1p = rs.b1r; h.b2p = rs.b2r; }
    return h;
}

__device__ __forceinline__ Coef make_coef(const RawS& g, const Halo& h, int tid)
{
    Coef c;
    const float a1w[6] = { h.a1m, g.a1.x, g.a1.y, g.a1.z, g.a1.w, h.a1p };
    const float b1w[6] = { h.b1m, g.b1.x, g.b1.y, g.b1.z, g.b1.w, h.b1p };
    c.b2w[0] = h.b2m; c.b2w[1] = g.b2.x; c.b2w[2] = g.b2.y;
    c.b2w[3] = g.b2.z; c.b2w[4] = g.b2.w; c.b2w[5] = h.b2p;
    #pragma unroll
    for (int e = 0; e < 4; ++e) {
        c.xp[e]  = 0.5f * (g.b0[e] - g.a0[e]);
        c.xm[e]  = 0.5f * (g.b0[e] + g.a0[e]);
        c.c0x[e] = -(g.b0[e] + b1w[e + 1]);
        c.cp[e]  = 0.5f * (b1w[e + 2] - a1w[e + 2]);
        c.cm[e]  = 0.5f * (a1w[e]     + b1w[e]);
    }
    if (tid == 0) {        // y=0 one-sided
        c.K[0] = -g.b0.x + 1.5f * g.a1.x + g.b1.x;
        c.K[1] = -2.0f * g.a1.y - 2.5f * g.b1.y;
        c.K[2] =  0.5f * g.a1.z + 2.0f * g.b1.z;
        c.K[3] = -0.5f * g.b1.w;
        c.T[0] = -0.75f * g.b2.x; c.T[1] = g.b2.y; c.T[2] = -0.25f * g.b2.z;
    }
    if (tid == 255) {      // y=NY-1 one-sided
        c.K[0] = -g.b0.w - 1.5f * g.a1.w + g.b1.w;
        c.K[1] =  2.0f * g.a1.z - 2.5f * g.b1.z;
        c.K[2] = -0.5f * g.a1.y + 2.0f * g.b1.y;
        c.K[3] = -0.5f * g.b1.x;
        c.T[0] = 0.75f * g.b2.w; c.T[1] = -g.b2.z; c.T[2] = 0.25f * g.b2.y;
    }
    return c;
}

__device__ __forceinline__ RowI convertI(const Coef& cf, const RawF& rf, int tid)
{
    const int lane = tid & 63;
    float fm = __shfl_up(rf.f.w, 1);
    float fp = __shfl_down(rf.f.x, 1);
    if (lane == 0)  fm = rf.fl;
    if (lane == 63) fp = rf.fr;
    const float fw[6] = { fm, rf.f.x, rf.f.y, rf.f.z, rf.f.w, fp };
    float te[6];
    #pragma unroll
    for (int w = 0; w < 6; ++w) te[w] = cf.b2w[w] * fw[w];
    RowI o;
    #pragma unroll
    for (int e = 0; e < 4; ++e) {
        const float d = 0.25f * (te[e + 2] - te[e]);
        o.fc[e] = fw[e + 1];
        o.ep[e] = fw[e + 1] * cf.xp[e]  + d;
        o.en[e] = fw[e + 1] * cf.xm[e]  - d;
        o.es[e] = fw[e + 1] * cf.c0x[e] + cf.cp[e] * fw[e + 2] + cf.cm[e] * fw[e];
    }
    if (tid == 0) {        // garbage fw[0] fully overridden here
        o.es[0] = cf.K[0] * fw[1] + cf.K[1] * fw[2] + cf.K[2] * fw[3] + cf.K[3] * fw[4];
        const float h = cf.T[0] * fw[1] + cf.T[1] * fw[2] + cf.T[2] * fw[3];
        o.ep[0] = fw[1] * cf.xp[0] + h;
        o.en[0] = fw[1] * cf.xm[0] - h;
    }
    if (tid == 255) {      // garbage fw[5] fully overridden here
        o.es[3] = cf.K[0] * fw[4] + cf.K[1] * fw[3] + cf.K[2] * fw[2] + cf.K[3] * fw[1];
        const float h = cf.T[0] * fw[4] + cf.T[1] * fw[3] + cf.T[2] * fw[2];
        o.ep[3] = fw[4] * cf.xp[3] + h;
        o.en[3] = fw[4] * cf.xm[3] - h;
    }
    return o;
}

__device__ __forceinline__ RowB convertB(const RawS& g, const Halo& h,
                                         const RawF& rf, int tid)
{
    const int lane = tid & 63;
    float fm = __shfl_up(rf.f.w, 1);
    float fp = __shfl_down(rf.f.x, 1);
    if (lane == 0)  fm = rf.fl;
    if (lane == 63) fp = rf.fr;
    const float fw[6] = { fm, rf.f.x, rf.f.y, rf.f.z, rf.f.w, fp };
    const float qe[6] = { h.a1m * fw[0], g.a1.x * fw[1], g.a1.y * fw[2],
                          g.a1.z * fw[3], g.a1.w * fw[4], h.a1p * fw[5] };
    const float se[6] = { h.b1m * fw[0], g.b1.x * fw[1], g.b1.y * fw[2],
                          g.b1.z * fw[3], g.b1.w * fw[4], h.b1p * fw[5] };
    const float te[6] = { h.b2m * fw[0], g.b2.x * fw[1], g.b2.y * fw[2],
                          g.b2.z * fw[3], g.b2.w * fw[4], h.b2p * fw[5] };
    RowB o;
    o.fc[0] = fw[1]; o.fc[1] = fw[2]; o.fc[2] = fw[3]; o.fc[3] = fw[4];
    o.pa[0] = g.a0.x * fw[1]; o.pa[1] = g.a0.y * fw[2];
    o.pa[2] = g.a0.z * fw[3]; o.pa[3] = g.a0.w * fw[4];
    o.rr[0] = g.b0.x * fw[1]; o.rr[1] = g.b0.y * fw[2];
    o.rr[2] = g.b0.z * fw[3]; o.rr[3] = g.b0.w * fw[4];
    #pragma unroll
    for (int i = 0; i < 4; ++i) {
        const float dq  = 0.5f * (qe[i + 2] - qe[i]);
        const float d2s = se[i + 2] - 2.0f * se[i + 1] + se[i];
        o.tt[i] = 0.5f * (te[i + 2] - te[i]);
        o.yc[i] = -dq + 0.5f * d2s;
    }
    if (tid == 0) {
        const float dq  = 0.5f * (-3.0f * qe[1] + 4.0f * qe[2] - qe[3]);
        const float d2s = 2.0f * se[1] - 5.0f * se[2] + 4.0f * se[3] - se[4];
        o.tt[0] = 0.5f * (-3.0f * te[1] + 4.0f * te[2] - te[3]);
        o.yc[0] = -dq + 0.5f * d2s;
    }
    if (tid == 255) {
        const float dq  = 0.5f * (3.0f * qe[4] - 4.0f * qe[3] + qe[2]);
        const float d2s = 2.0f * se[4] - 5.0f * se[3] + 4.0f * se[2] - se[1];
        o.tt[3] = 0.5f * (3.0f * te[4] - 4.0f * te[3] + te[2]);
        o.yc[3] = -dq + 0.5f * d2s;
    }
    return o;
}

__global__ __launch_bounds__(256) void fp2d_kernel(
    const float* __restrict__ f,
    const float* __restrict__ Ag,
    const float* __restrict__ Bg,
    const float* __restrict__ dt,
    float* __restrict__ out)
{
    const int tid = threadIdx.x;
    const int y0  = tid * 4;
    const int x0  = blockIdx.x * CHUNK;     // xc fastest -> XCD-local grid reuse
    const int bb  = blockIdx.y * NB;

    const float* __restrict__ A0 = Ag;
    const float* __restrict__ A1 = Ag + PLANE;
    const float* __restrict__ B0 = Bg;
    const float* __restrict__ B1 = Bg + PLANE;
    const float* __restrict__ B2 = Bg + 2 * PLANE;

    const float* fb[NB];
    float* ob[NB];
    float dtb[NB];
    #pragma unroll
    for (int j = 0; j < NB; ++j) {
        fb[j]  = f   + (size_t)(bb + j) * PLANE;
        ob[j]  = out + (size_t)(bb + j) * PLANE;
        dtb[j] = dt[bb + j];
    }

    const int cs = (x0 == 0) ? 1 : x0;
    const int ce = (x0 + CHUNK == NX) ? NX - 2 : x0 + CHUNK - 1;

    // Persistent per-batch state: m-row needs only en; c-row needs es/en/fc.
    float mEn[NB][4], cEs[NB][4], cEn[NB][4], cFc[NB][4];

    // Prologue: rows cs-1 and cs converted; row cs+1 raw (prefetched)
    RawS sP;
    RawF fP[NB];
    {
        RawS sM = load_rawS(cs - 1, y0, tid, A0, A1, B0, B1, B2);
        RawS sC = load_rawS(cs,     y0, tid, A0, A1, B0, B1, B2);
        sP      = load_rawS(cs + 1, y0, tid, A0, A1, B0, B1, B2);
        const Coef cfM = make_coef(sM, make_halo(sM, tid), tid);
        const Coef cfC = make_coef(sC, make_halo(sC, tid), tid);
        #pragma unroll
        for (int j = 0; j < NB; ++j) {
            RawF fMj = load_rawF(cs - 1, y0, tid, fb[j]);
            RawF fCj = load_rawF(cs,     y0, tid, fb[j]);
            fP[j]    = load_rawF(cs + 1, y0, tid, fb[j]);
            RowI rm = convertI(cfM, fMj, tid);
            RowI rc = convertI(cfC, fCj, tid);
            #pragma unroll
            for (int i = 0; i < 4; ++i) {
                mEn[j][i] = rm.en[i];
                cEs[j][i] = rc.es[i]; cEn[j][i] = rc.en[i]; cFc[j][i] = rc.fc[i];
            }
        }
    }

    for (int x = cs; x <= ce; ++x) {
        const int xn = (x + 2 < NX) ? x + 2 : NX - 1;
        RawS sN = load_rawS(xn, y0, tid, A0, A1, B0, B1, B2);   // prefetch
        RawF fN[NB];
        #pragma unroll
        for (int j = 0; j < NB; ++j) fN[j] = load_rawF(xn, y0, tid, fb[j]);

        const Halo hP = make_halo(sP, tid);
        const Coef cf = make_coef(sP, hP, tid);   // shared across NB batches
        #pragma unroll
        for (int j = 0; j < NB; ++j) {
            RowI rp = convertI(cf, fP[j], tid);
            v4f o;
            #pragma unroll
            for (int i = 0; i < 4; ++i) {
                const float t = rp.ep[i] + cEs[j][i] + mEn[j][i];
                o[i] = fmaxf(fmaf(t, dtb[j], cFc[j][i]), 0.0f);
            }
            *(v4f*)(ob[j] + x * NY + y0) = o;   // A/B: plain cached store (was NT)
            #pragma unroll
            for (int i = 0; i < 4; ++i) {
                mEn[j][i] = cEn[j][i];
                cEs[j][i] = rp.es[i]; cEn[j][i] = rp.en[i]; cFc[j][i] = rp.fc[i];
            }
        }
        sP = sN;
        #pragma unroll
        for (int j = 0; j < NB; ++j) fP[j] = fN[j];
    }

    // x = 0 one-sided (first chunk only): row-by-row accumulation.
    // df = yc(r0) + sum_r wP[r]*pa_r + wR[r]*rr_r + wT[r]*tt_r
    if (x0 == 0) {
        const float wPx[4] = {  1.5f, -2.0f,  0.5f,  0.0f };
        const float wRx[4] = {  1.0f, -2.5f,  2.0f, -0.5f };
        const float wTx[4] = { -1.5f,  2.0f, -0.5f,  0.0f };
        float acc[NB][4], fc0[NB][4];
        #pragma unroll
        for (int r = 0; r < 4; ++r) {
            RawS g = load_rawS(r, y0, tid, A0, A1, B0, B1, B2);
            Halo h = make_halo(g, tid);
            #pragma unroll
            for (int j = 0; j < NB; ++j) {
                RowB rb = convertB(g, h, load_rawF(r, y0, tid, fb[j]), tid);
                #pragma unroll
                for (int i = 0; i < 4; ++i) {
                    if (r == 0) { acc[j][i] = rb.yc[i]; fc0[j][i] = rb.fc[i]; }
                    acc[j][i] += wPx[r] * rb.pa[i] + wRx[r] * rb.rr[i] + wTx[r] * rb.tt[i];
                }
            }
        }
        #pragma unroll
        for (int j = 0; j < NB; ++j) {
            v4f o;
            #pragma unroll
            for (int i = 0; i < 4; ++i)
                o[i] = fmaxf(fmaf(acc[j][i], dtb[j], fc0[j][i]), 0.0f);
            *(v4f*)(ob[j] + y0) = o;            // plain store
        }
    }

    // x = NX-1 one-sided (last chunk only)
    if (x0 + CHUNK == NX) {
        const float wPx[4] = { -1.5f,  2.0f, -0.5f,  0.0f };
        const float wRx[4] = {  1.0f, -2.5f,  2.0f, -0.5f };
        const float wTx[4] = {  1.5f, -2.0f,  0.5f,  0.0f };
        float acc[NB][4], fc0[NB][4];
        #pragma unroll
        for (int r = 0; r < 4; ++r) {
            RawS g = load_rawS(NX - 1 - r, y0, tid, A0, A1, B0, B1, B2);
            Halo h = make_halo(g, tid);
            #pragma unroll
            for (int j = 0; j < NB; ++j) {
                RowB rb = convertB(g, h, load_rawF(NX - 1 - r, y0, tid, fb[j]), tid);
                #pragma unroll
                for (int i = 0; i < 4; ++i) {
                    if (r == 0) { acc[j][i] = rb.yc[i]; fc0[j][i] = rb.fc[i]; }
                    acc[j][i] += wPx[r] * rb.pa[i] + wRx[r] * rb.rr[i] + wTx[r] * rb.tt[i];
                }
            }
        }
        #pragma unroll
        for (int j = 0; j < NB; ++j) {
            v4f o;
            #pragma unroll
            for (int i = 0; i < 4; ++i)
                o[i] = fmaxf(fmaf(acc[j][i], dtb[j], fc0[j][i]), 0.0f);
            *(v4f*)(ob[j] + (size_t)(NX - 1) * NY + y0) = o;   // plain store
        }
    }
}

extern "C" void kernel_launch(void* const* d_in, const int* in_sizes, int n_in,
                              void* d_out, int out_size, void* d_ws, size_t ws_size,
                              hipStream_t stream) {
    const float* f  = (const float*)d_in[0];
    const float* Ag = (const float*)d_in[1];
    const float* Bg = (const float*)d_in[2];
    const float* dt = (const float*)d_in[3];
    float* out = (float*)d_out;

    dim3 block(256, 1, 1);
    dim3 grid(NX / CHUNK, BATCH / NB, 1);
    fp2d_kernel<<<grid, block, 0, stream>>>(f, Ag, Bg, dt, out);
}